// Round 9
// baseline (238.912 us; speedup 1.0000x reference)
//
#include <hip/hip_runtime.h>
#include <hip/hip_bf16.h>

using bf16 = __hip_bfloat16;
typedef __attribute__((ext_vector_type(8))) short frag_ab;   // 8 bf16
typedef __attribute__((ext_vector_type(4))) float frag_cd;   // 4 fp32

constexpr float TEMP   = 0.07f;
constexpr float INVT   = 1.0f / TEMP;                 // fixed logsumexp shift
constexpr float THRESH = 0.1f;
constexpr float EPS    = 1e-8f;
constexpr float LOG2E  = 1.4426950408889634f;
constexpr float C1     = LOG2E / TEMP;                // exp((s-1)/T) = exp2(s*C1 - C1)

constexpr int D  = 128;
constexpr int TC = 128;   // tile size (rows and cols): block (R,C) does a 128x128 tile

__device__ __forceinline__ frag_cd mfma16(frag_ab a, frag_ab b, frag_cd c) {
    return __builtin_amdgcn_mfma_f32_16x16x32_bf16(a, b, c, 0, 0, 0);
}

// async global->LDS DMA, 16B per lane, LDS dest = wave-uniform base + lane*16
__device__ __forceinline__ void async_copy16(const bf16* gp, bf16* lp) {
    __builtin_amdgcn_global_load_lds(
        (__attribute__((address_space(1))) void*)(gp),
        (__attribute__((address_space(3))) void*)(lp), 16, 0, 0);
}

// ------- kernel 1: row-normalize -> bf16, diagonal dot, zero-init acc/counter -------
__global__ __launch_bounds__(256) void k1_normalize(
    const float* __restrict__ f, bf16* __restrict__ fn,
    float* __restrict__ diag, float* __restrict__ acc,
    unsigned* __restrict__ counter, int n)
{
    if (blockIdx.x == 0 && threadIdx.x == 0) { acc[0] = 0.f; counter[0] = 0u; }
    const int row  = blockIdx.x * 4 + (threadIdx.x >> 6);
    const int lane = threadIdx.x & 63;
    float2 v = ((const float2*)(f + (size_t)row * D))[lane];
    float ss = v.x * v.x + v.y * v.y;
    #pragma unroll
    for (int m = 32; m >= 1; m >>= 1) ss += __shfl_xor(ss, m, 64);
    const float inv = 1.0f / fmaxf(sqrtf(ss), EPS);
    __hip_bfloat162 o;
    o.x = __float2bfloat16(v.x * inv);
    o.y = __float2bfloat16(v.y * inv);
    ((__hip_bfloat162*)(fn + (size_t)row * D))[lane] = o;
    // diagonal raw dot of the bf16-rounded row (matches MFMA s_ii to ~1e-6)
    const float a = __bfloat162float(o.x), b = __bfloat162float(o.y);
    float p = a * a + b * b;
    #pragma unroll
    for (int m = 32; m >= 1; m >>= 1) p += __shfl_xor(p, m, 64);
    if (lane == 0) diag[row] = p;
}

// ---------------- kernel 2: SYMMETRIC fused sim + masked reductions ----------------
// Upper triangle of 128x128 tiles (2080 blocks). Block (R,C), C>=R, credits both
// endpoints via disjoint partial-split slots (R8-verified, absmax 0):
//   row-side -> split C, rows in R ; col-side -> split R, rows in C (off-diag only).
//
// R8 post-mortem: per-sub cost was 2.5x R5's because the col-side quad-reduce put a
// ~300-cyc DEPENDENT ds_permute chain (2-deep shfl_xor x3) inside every sub — in-order
// issue stalls the wave before the next sub's ds_reads. Fix: fire-and-forget LDS
// atomics (ds_add_f32, no return -> nothing waits on them). Row-side reduce likewise
// becomes LDS atomics -> coalesced final stores by 128 threads.
// Sum-reorder tolerance proven by R6 (atomic variant passed absmax 0.0).
// LAUNCH-BOUNDS LAW (R0/R2/R4/R7): arch-VGPR cap = 256/min_waves; live ~110 regs ->
// (256,2) [128 cap]. LDS 36.4KB -> 4 blocks/CU (same as VGPR limit). DO NOT RAISE.
__global__ __launch_bounds__(256, 2) void k2_main(
    const bf16* __restrict__ fn, const float* __restrict__ lab,
    float* __restrict__ se_p, float* __restrict__ sp_p,
    float* __restrict__ cnt_p, int n, int nb)
{
    // linear triangle decode: bid -> (Rb, Cb), 0 <= Rb <= Cb < nb
    const int bid = blockIdx.x;
    int Rb = (int)floorf(((2.0f * nb + 1.0f)
              - sqrtf((2.0f * nb + 1.0f) * (2.0f * nb + 1.0f) - 8.0f * (float)bid)) * 0.5f);
    while ((Rb + 1) * (2 * nb - Rb) / 2 <= bid) ++Rb;       // f32 decode correction
    while (Rb * (2 * nb - Rb + 1) / 2 > bid) --Rb;
    const int Cb = Rb + (bid - Rb * (2 * nb - Rb + 1) / 2);
    const bool diagblk = (Cb == Rb);

    __shared__ bf16  colbuf[TC * D];   // 32 KB, swizzled: col c slot s holds chunk s^(c&15)
    __shared__ float lab_s[TC];
    __shared__ float sums[6][TC];      // [0..2] row-side se/sp/cnt, [3..5] col-side; 3 KB

    const int tid  = threadIdx.x;
    const int wave = tid >> 6;
    const int lane = tid & 63;
    const int quad = lane >> 4;
    const int l15  = lane & 15;

    const int row_base = Rb * TC + wave * 32;
    const int col_base = Cb * TC;

    if (tid < TC) lab_s[tid] = lab[col_base + tid];
    for (int i = tid; i < 6 * TC; i += 256) (&sums[0][0])[i] = 0.f;

    // DMA the col tile: 8 issues/wave, issue i lane l -> LDS byte wave*8192+i*1024+l*16
    //   col ci = wave*32 + i*4 + (l>>4), slot l&15, source chunk = l15 ^ (ci&15)
    {
        const bf16* gt = fn + (size_t)col_base * D;
        bf16* lb = &colbuf[wave * 4096];
        #pragma unroll
        for (int i = 0; i < 8; ++i) {
            const int ci = wave * 32 + i * 4 + (lane >> 4);
            const int ki = l15 ^ (ci & 15);
            async_copy16(gt + (size_t)ci * D + ki * 8, lb + i * 512);
        }
    }

    // A fragments (overlap the DMA): set s covers rows row_base+s*16+l15, k=kb*32+quad*8+j
    frag_ab afr[2][4];
    #pragma unroll
    for (int s = 0; s < 2; ++s) {
        const bf16* ap = fn + (size_t)(row_base + s * 16 + l15) * D + quad * 8;
        #pragma unroll
        for (int kb = 0; kb < 4; ++kb) afr[s][kb] = *(const frag_ab*)(ap + kb * 32);
    }
    float li[2][4];
    #pragma unroll
    for (int s = 0; s < 2; ++s)
        #pragma unroll
        for (int r = 0; r < 4; ++r)
            li[s][r] = lab[row_base + s * 16 + quad * 4 + r];

    float se[2][4] = {}, sp[2][4] = {}, cnt[2][4] = {};

    __syncthreads();   // drains DMA vmcnt; colbuf + lab_s + zeroed sums ready

    #pragma unroll
    for (int sub = 0; sub < 8; ++sub) {
        const int c = sub * 16 + l15;          // column within tile (c&15 == l15)
        frag_ab b[4];
        #pragma unroll
        for (int kb = 0; kb < 4; ++kb)
            b[kb] = *(const frag_ab*)(&colbuf[(size_t)c * D + (((quad + 4 * kb) ^ l15) * 8)]);
        frag_cd a0 = {0.f, 0.f, 0.f, 0.f}, a1 = {0.f, 0.f, 0.f, 0.f};
        #pragma unroll
        for (int kb = 0; kb < 4; ++kb) {
            a0 = mfma16(afr[0][kb], b[kb], a0);
            a1 = mfma16(afr[1][kb], b[kb], a1);
        }
        const float lj = lab_s[c];
        float cs_e = 0.f, cs_sp = 0.f, cs_cnt = 0.f;
        #pragma unroll
        for (int s = 0; s < 2; ++s) {
            const frag_cd& acc = s ? a1 : a0;
            #pragma unroll
            for (int r = 0; r < 4; ++r) {
                const float sv = acc[r];                      // raw dot (cosine)
                const float e  = __builtin_amdgcn_exp2f(__builtin_fmaf(sv, C1, -C1));
                const float pm = (fabsf(li[s][r] - lj) < THRESH) ? 1.0f : 0.0f;
                se[s][r]  += e;
                sp[s][r]   = __builtin_fmaf(pm, sv, sp[s][r]); // raw dots; 1/T in k3
                cnt[s][r] += pm;
                cs_e  += e;                                    // col-side (symmetric credit)
                cs_sp  = __builtin_fmaf(pm, sv, cs_sp);
                cs_cnt += pm;
            }
        }
        // fire-and-forget LDS atomics: no lane ever WAITS on these inside the loop
        if (!diagblk) {
            atomicAdd(&sums[3][c], cs_e);
            atomicAdd(&sums[4][c], cs_sp);
            atomicAdd(&sums[5][c], cs_cnt);
        }
    }

    // row-side: LDS atomics (16 lanes/quad share a row; rows disjoint across waves)
    #pragma unroll
    for (int s = 0; s < 2; ++s)
        #pragma unroll
        for (int r = 0; r < 4; ++r) {
            const int ri = wave * 32 + s * 16 + quad * 4 + r;   // row within tile
            atomicAdd(&sums[0][ri], se[s][r]);
            atomicAdd(&sums[1][ri], sp[s][r]);
            atomicAdd(&sums[2][ri], cnt[s][r]);
        }

    __syncthreads();   // all LDS atomics done

    // coalesced final stores by 128 threads (row-side -> split Cb; col-side -> split Rb)
    if (tid < TC) {
        const size_t ro = (size_t)Cb * n + Rb * TC + tid;
        se_p[ro]  = sums[0][tid];
        sp_p[ro]  = sums[1][tid];
        cnt_p[ro] = sums[2][tid];
        if (!diagblk) {
            const size_t co = (size_t)Rb * n + col_base + tid;
            se_p[co]  = sums[3][tid];
            sp_p[co]  = sums[4][tid];
            cnt_p[co] = sums[5][tid];
        }
    }
}

// ------- kernel 3: per-row finalize (64 splits, wave-split + unrolled) + grid reduce -------
// R8 post-mortem: runtime-bounded 64-iter loop on 32 blocks was latency-serialized.
// Now: 128 blocks; block handles 64 rows; wave w sums splits [16w,16w+16) (unrolled,
// 48 independent loads in flight); 4-wave LDS combine; wave 0 finalizes.
__global__ __launch_bounds__(256) void k3_finalize(
    const float* __restrict__ diag, const float* __restrict__ se_p,
    const float* __restrict__ sp_p, const float* __restrict__ cnt_p,
    float* __restrict__ acc, unsigned* __restrict__ counter,
    float* __restrict__ out, int n, int nb)
{
    const int tid  = threadIdx.x;
    const int wave = tid >> 6;
    const int lane = tid & 63;
    const int row  = blockIdx.x * 64 + lane;

    float se = 0.f, sp = 0.f, cnt = 0.f;
    #pragma unroll
    for (int k = 0; k < 16; ++k) {
        const int s = wave * 16 + k;
        se  += se_p[(size_t)s * n + row];
        sp  += sp_p[(size_t)s * n + row];
        cnt += cnt_p[(size_t)s * n + row];
    }
    __shared__ float part[3][4][64];
    part[0][wave][lane] = se;
    part[1][wave][lane] = sp;
    part[2][wave][lane] = cnt;
    __syncthreads();
    if (wave == 0) {
        se  = part[0][0][lane] + part[0][1][lane] + part[0][2][lane] + part[0][3][lane];
        sp  = part[1][0][lane] + part[1][1][lane] + part[1][2][lane] + part[1][3][lane];
        cnt = part[2][0][lane] + part[2][1][lane] + part[2][2][lane] + part[2][3][lane];
        const float s_ii = diag[row];
        se  -= __builtin_amdgcn_exp2f(__builtin_fmaf(s_ii, C1, -C1));
        sp  -= s_ii;
        cnt -= 1.0f;
        float loss = INVT + __logf(se) - (sp * INVT) / fmaxf(cnt, 1.0f);
        #pragma unroll
        for (int m = 32; m >= 1; m >>= 1) loss += __shfl_xor(loss, m, 64);
        if (lane == 0) {
            atomicAdd(acc, loss);
            __threadfence();
            const unsigned old = atomicAdd(counter, 1u);
            if (old == gridDim.x - 1) {
                const float total = atomicAdd(acc, 0.0f);  // atomic load, same-address order
                out[0] = total / (float)n;
            }
        }
    }
}

extern "C" void kernel_launch(void* const* d_in, const int* in_sizes, int n_in,
                              void* d_out, int out_size, void* d_ws, size_t ws_size,
                              hipStream_t stream) {
    const float* feat = (const float*)d_in[0];
    const float* lab  = (const float*)d_in[1];
    const int n = in_sizes[1];              // 8192
    const int nb = n / TC;                  // 64 block-rows
    float* out = (float*)d_out;

    // ws: fn (n*D bf16 = 2MB) | diag (n f32) | se_p | sp_p | cnt_p (each nb*n f32 = 2MB)
    //     | acc | counter
    char* ws = (char*)d_ws;
    bf16* fn = (bf16*)ws;
    size_t off = (size_t)n * D * sizeof(bf16);
    float* diag  = (float*)(ws + off); off += (size_t)n * sizeof(float);
    float* se_p  = (float*)(ws + off); off += (size_t)nb * n * sizeof(float);
    float* sp_p  = (float*)(ws + off); off += (size_t)nb * n * sizeof(float);
    float* cnt_p = (float*)(ws + off); off += (size_t)nb * n * sizeof(float);
    float* acc   = (float*)(ws + off); off += sizeof(float);
    unsigned* counter = (unsigned*)(ws + off);

    k1_normalize<<<n / 4, 256, 0, stream>>>(feat, fn, diag, acc, counter, n);
    const int ntri = nb * (nb + 1) / 2;     // 2080 live tiles
    k2_main<<<ntri, 256, 0, stream>>>(fn, lab, se_p, sp_p, cnt_p, n, nb);
    k3_finalize<<<n / 64, 256, 0, stream>>>(diag, se_p, sp_p, cnt_p, acc, counter, out, n, nb);
}

// Round 10
// 100.183 us; speedup vs baseline: 2.3847x; 2.3847x over previous
//
#include <hip/hip_runtime.h>
#include <hip/hip_bf16.h>

using bf16 = __hip_bfloat16;
typedef __attribute__((ext_vector_type(8))) short frag_ab;   // 8 bf16
typedef __attribute__((ext_vector_type(4))) float frag_cd;   // 4 fp32

constexpr float TEMP   = 0.07f;
constexpr float INVT   = 1.0f / TEMP;                 // fixed logsumexp shift
constexpr float THRESH = 0.1f;
constexpr float EPS    = 1e-8f;
constexpr float LOG2E  = 1.4426950408889634f;
constexpr float C1     = LOG2E / TEMP;                // exp((s-1)/T) = exp2(s*C1 - C1)

constexpr int D  = 128;
constexpr int TC = 128;   // tile size (rows and cols): block (R,C) does a 128x128 tile

__device__ __forceinline__ frag_cd mfma16(frag_ab a, frag_ab b, frag_cd c) {
    return __builtin_amdgcn_mfma_f32_16x16x32_bf16(a, b, c, 0, 0, 0);
}

// async global->LDS DMA, 16B per lane, LDS dest = wave-uniform base + lane*16
__device__ __forceinline__ void async_copy16(const bf16* gp, bf16* lp) {
    __builtin_amdgcn_global_load_lds(
        (__attribute__((address_space(1))) void*)(gp),
        (__attribute__((address_space(3))) void*)(lp), 16, 0, 0);
}

// ------- kernel 1: row-normalize -> bf16, diagonal dot, zero-init acc/counter -------
__global__ __launch_bounds__(256) void k1_normalize(
    const float* __restrict__ f, bf16* __restrict__ fn,
    float* __restrict__ diag, float* __restrict__ acc,
    unsigned* __restrict__ counter, int n)
{
    if (blockIdx.x == 0 && threadIdx.x == 0) { acc[0] = 0.f; counter[0] = 0u; }
    const int row  = blockIdx.x * 4 + (threadIdx.x >> 6);
    const int lane = threadIdx.x & 63;
    float2 v = ((const float2*)(f + (size_t)row * D))[lane];
    float ss = v.x * v.x + v.y * v.y;
    #pragma unroll
    for (int m = 32; m >= 1; m >>= 1) ss += __shfl_xor(ss, m, 64);
    const float inv = 1.0f / fmaxf(sqrtf(ss), EPS);
    __hip_bfloat162 o;
    o.x = __float2bfloat16(v.x * inv);
    o.y = __float2bfloat16(v.y * inv);
    ((__hip_bfloat162*)(fn + (size_t)row * D))[lane] = o;
    // diagonal raw dot of the bf16-rounded row (matches MFMA s_ii to ~1e-6)
    const float a = __bfloat162float(o.x), b = __bfloat162float(o.y);
    float p = a * a + b * b;
    #pragma unroll
    for (int m = 32; m >= 1; m >>= 1) p += __shfl_xor(p, m, 64);
    if (lane == 0) diag[row] = p;
}

// ---------------- kernel 2: SYMMETRIC fused sim + masked reductions ----------------
// Upper triangle of 128x128 tiles (2080 blocks). Block (R,C), C>=R, credits both
// endpoints via disjoint partial-split slots (R8-verified, absmax 0):
//   row-side -> split C, rows in R ; col-side -> split R, rows in C (off-diag only).
//
// Delivery-mechanism history (the symmetry win kept getting eaten):
//   R6 global atomics: cross-XCD fabric RMW, 142 MB      -> k2 103us
//   R8 in-loop shfl chains: ~300cy dependent DS chain/sub -> k2  41us
//   R9 LDS atomics: 16 same-address ds_add serialize      -> k2 177us
// RULE: nothing cross-lane or contended inside the sub loop. Col-side partials are
// now plain PRIVATE ds_writes (one lane owns each (slot,col) cell — zero contention,
// fire-and-forget); one post-loop pass sums the 16 slots per column. Row-side uses
// the champion's post-loop butterfly. LDS 59.4KB -> 2 blocks/CU (accepted: the loop's
// VALU floor dominates; in-loop stalls mattered more than residency).
// LAUNCH-BOUNDS LAW (R0/R2/R4/R7): cap = 256/min_waves; live ~106 regs -> (256,2).
__global__ __launch_bounds__(256, 2) void k2_main(
    const bf16* __restrict__ fn, const float* __restrict__ lab,
    float* __restrict__ se_p, float* __restrict__ sp_p,
    float* __restrict__ cnt_p, int n, int nb)
{
    // linear triangle decode: bid -> (Rb, Cb), 0 <= Rb <= Cb < nb
    const int bid = blockIdx.x;
    int Rb = (int)floorf(((2.0f * nb + 1.0f)
              - sqrtf((2.0f * nb + 1.0f) * (2.0f * nb + 1.0f) - 8.0f * (float)bid)) * 0.5f);
    while ((Rb + 1) * (2 * nb - Rb) / 2 <= bid) ++Rb;       // f32 decode correction
    while (Rb * (2 * nb - Rb + 1) / 2 > bid) --Rb;
    const int Cb = Rb + (bid - Rb * (2 * nb - Rb + 1) / 2);
    const bool diagblk = (Cb == Rb);

    __shared__ bf16  colbuf[TC * D];     // 32 KB, swizzled: col c slot s holds chunk s^(c&15)
    __shared__ float lab_s[TC];
    __shared__ float csum[3][16][136];   // [qty][wave*4+quad][col], pad 136: 2-way bank = free

    const int tid  = threadIdx.x;
    const int wave = tid >> 6;
    const int lane = tid & 63;
    const int quad = lane >> 4;
    const int l15  = lane & 15;
    const int wq   = wave * 4 + quad;

    const int row_base = Rb * TC + wave * 32;
    const int col_base = Cb * TC;

    if (tid < TC) lab_s[tid] = lab[col_base + tid];

    // DMA the col tile: 8 issues/wave, issue i lane l -> LDS byte wave*8192+i*1024+l*16
    //   col ci = wave*32 + i*4 + (l>>4), slot l&15, source chunk = l15 ^ (ci&15)
    {
        const bf16* gt = fn + (size_t)col_base * D;
        bf16* lb = &colbuf[wave * 4096];
        #pragma unroll
        for (int i = 0; i < 8; ++i) {
            const int ci = wave * 32 + i * 4 + (lane >> 4);
            const int ki = l15 ^ (ci & 15);
            async_copy16(gt + (size_t)ci * D + ki * 8, lb + i * 512);
        }
    }

    // A fragments (overlap the DMA): set s covers rows row_base+s*16+l15, k=kb*32+quad*8+j
    frag_ab afr[2][4];
    #pragma unroll
    for (int s = 0; s < 2; ++s) {
        const bf16* ap = fn + (size_t)(row_base + s * 16 + l15) * D + quad * 8;
        #pragma unroll
        for (int kb = 0; kb < 4; ++kb) afr[s][kb] = *(const frag_ab*)(ap + kb * 32);
    }
    float li[2][4];
    #pragma unroll
    for (int s = 0; s < 2; ++s)
        #pragma unroll
        for (int r = 0; r < 4; ++r)
            li[s][r] = lab[row_base + s * 16 + quad * 4 + r];

    float se[2][4] = {}, sp[2][4] = {}, cnt[2][4] = {};

    __syncthreads();   // drains DMA vmcnt; colbuf + lab_s ready

    #pragma unroll
    for (int sub = 0; sub < 8; ++sub) {
        const int c = sub * 16 + l15;          // column within tile (c&15 == l15)
        frag_ab b[4];
        #pragma unroll
        for (int kb = 0; kb < 4; ++kb)
            b[kb] = *(const frag_ab*)(&colbuf[(size_t)c * D + (((quad + 4 * kb) ^ l15) * 8)]);
        frag_cd a0 = {0.f, 0.f, 0.f, 0.f}, a1 = {0.f, 0.f, 0.f, 0.f};
        #pragma unroll
        for (int kb = 0; kb < 4; ++kb) {
            a0 = mfma16(afr[0][kb], b[kb], a0);
            a1 = mfma16(afr[1][kb], b[kb], a1);
        }
        const float lj = lab_s[c];
        float cs_e = 0.f, cs_sp = 0.f, cs_cnt = 0.f;
        #pragma unroll
        for (int s = 0; s < 2; ++s) {
            const frag_cd& acc = s ? a1 : a0;
            #pragma unroll
            for (int r = 0; r < 4; ++r) {
                const float sv = acc[r];                      // raw dot (cosine)
                const float e  = __builtin_amdgcn_exp2f(__builtin_fmaf(sv, C1, -C1));
                const float pm = (fabsf(li[s][r] - lj) < THRESH) ? 1.0f : 0.0f;
                se[s][r]  += e;
                sp[s][r]   = __builtin_fmaf(pm, sv, sp[s][r]); // raw dots; 1/T in k3
                cnt[s][r] += pm;
                cs_e  += e;                                    // col-side (symmetric credit)
                cs_sp  = __builtin_fmaf(pm, sv, cs_sp);
                cs_cnt += pm;
            }
        }
        // PRIVATE plain ds_writes — one lane owns (wq,c); no contention, nothing waits
        if (!diagblk) {
            csum[0][wq][c] = cs_e;
            csum[1][wq][c] = cs_sp;
            csum[2][wq][c] = cs_cnt;
        }
    }

    // row-side: butterfly across the 16 lanes of each quad-group -> split Cb (plain stores)
    #pragma unroll
    for (int s = 0; s < 2; ++s)
        #pragma unroll
        for (int r = 0; r < 4; ++r) {
            #pragma unroll
            for (int m = 1; m < 16; m <<= 1) {
                se[s][r]  += __shfl_xor(se[s][r],  m, 64);
                sp[s][r]  += __shfl_xor(sp[s][r],  m, 64);
                cnt[s][r] += __shfl_xor(cnt[s][r], m, 64);
            }
        }
    if (l15 == 0) {
        #pragma unroll
        for (int s = 0; s < 2; ++s)
            #pragma unroll
            for (int r = 0; r < 4; ++r) {
                const int i = row_base + s * 16 + quad * 4 + r;
                se_p[(size_t)Cb * n + i]  = se[s][r];
                sp_p[(size_t)Cb * n + i]  = sp[s][r];
                cnt_p[(size_t)Cb * n + i] = cnt[s][r];
            }
    }

    // col-side combine -> split Rb (off-diag only; diagblk is block-uniform -> barrier safe)
    if (!diagblk) {
        __syncthreads();                       // csum writes visible
        if (tid < TC) {
            float ve = 0.f, vs = 0.f, vc = 0.f;
            #pragma unroll
            for (int k = 0; k < 16; ++k) {
                ve += csum[0][k][tid];
                vs += csum[1][k][tid];
                vc += csum[2][k][tid];
            }
            se_p[(size_t)Rb * n + col_base + tid]  = ve;
            sp_p[(size_t)Rb * n + col_base + tid]  = vs;
            cnt_p[(size_t)Rb * n + col_base + tid] = vc;
        }
    }
}

// ------- kernel 3: per-row finalize (64 splits, wave-split + unrolled) + grid reduce -------
__global__ __launch_bounds__(256) void k3_finalize(
    const float* __restrict__ diag, const float* __restrict__ se_p,
    const float* __restrict__ sp_p, const float* __restrict__ cnt_p,
    float* __restrict__ acc, unsigned* __restrict__ counter,
    float* __restrict__ out, int n, int nb)
{
    const int tid  = threadIdx.x;
    const int wave = tid >> 6;
    const int lane = tid & 63;
    const int row  = blockIdx.x * 64 + lane;

    float se = 0.f, sp = 0.f, cnt = 0.f;
    #pragma unroll
    for (int k = 0; k < 16; ++k) {
        const int s = wave * 16 + k;
        se  += se_p[(size_t)s * n + row];
        sp  += sp_p[(size_t)s * n + row];
        cnt += cnt_p[(size_t)s * n + row];
    }
    __shared__ float part[3][4][64];
    part[0][wave][lane] = se;
    part[1][wave][lane] = sp;
    part[2][wave][lane] = cnt;
    __syncthreads();
    if (wave == 0) {
        se  = part[0][0][lane] + part[0][1][lane] + part[0][2][lane] + part[0][3][lane];
        sp  = part[1][0][lane] + part[1][1][lane] + part[1][2][lane] + part[1][3][lane];
        cnt = part[2][0][lane] + part[2][1][lane] + part[2][2][lane] + part[2][3][lane];
        const float s_ii = diag[row];
        se  -= __builtin_amdgcn_exp2f(__builtin_fmaf(s_ii, C1, -C1));
        sp  -= s_ii;
        cnt -= 1.0f;
        float loss = INVT + __logf(se) - (sp * INVT) / fmaxf(cnt, 1.0f);
        #pragma unroll
        for (int m = 32; m >= 1; m >>= 1) loss += __shfl_xor(loss, m, 64);
        if (lane == 0) {
            atomicAdd(acc, loss);
            __threadfence();
            const unsigned old = atomicAdd(counter, 1u);
            if (old == gridDim.x - 1) {
                const float total = atomicAdd(acc, 0.0f);  // atomic load, same-address order
                out[0] = total / (float)n;
            }
        }
    }
}

extern "C" void kernel_launch(void* const* d_in, const int* in_sizes, int n_in,
                              void* d_out, int out_size, void* d_ws, size_t ws_size,
                              hipStream_t stream) {
    const float* feat = (const float*)d_in[0];
    const float* lab  = (const float*)d_in[1];
    const int n = in_sizes[1];              // 8192
    const int nb = n / TC;                  // 64 block-rows
    float* out = (float*)d_out;

    // ws: fn (n*D bf16 = 2MB) | diag (n f32) | se_p | sp_p | cnt_p (each nb*n f32 = 2MB)
    //     | acc | counter
    char* ws = (char*)d_ws;
    bf16* fn = (bf16*)ws;
    size_t off = (size_t)n * D * sizeof(bf16);
    float* diag  = (float*)(ws + off); off += (size_t)n * sizeof(float);
    float* se_p  = (float*)(ws + off); off += (size_t)nb * n * sizeof(float);
    float* sp_p  = (float*)(ws + off); off += (size_t)nb * n * sizeof(float);
    float* cnt_p = (float*)(ws + off); off += (size_t)nb * n * sizeof(float);
    float* acc   = (float*)(ws + off); off += sizeof(float);
    unsigned* counter = (unsigned*)(ws + off);

    k1_normalize<<<n / 4, 256, 0, stream>>>(feat, fn, diag, acc, counter, n);
    const int ntri = nb * (nb + 1) / 2;     // 2080 live tiles
    k2_main<<<ntri, 256, 0, stream>>>(fn, lab, se_p, sp_p, cnt_p, n, nb);
    k3_finalize<<<n / 64, 256, 0, stream>>>(diag, se_p, sp_p, cnt_p, acc, counter, out, n, nb);
}